// Round 1
// baseline (6790.817 us; speedup 1.0000x reference)
//
#include <hip/hip_runtime.h>
#include <cmath>

// ---------------------------------------------------------------------------
// ConvFrameDecoder — fp32 correctness-first implementation.
// Greedy argmax feedback (e_t = emb_w[argmax]) forces fp32 precision on the
// whole recurrent chain; bf16 anywhere would flip argmaxes vs the reference.
// Structure:
//   prep:     fold BN into (a,b); transpose conv/actor/emb weights; b_ih+b_hh
//   init:     xcat h/e slots, c buffer
//   visconv:  per-image conv1+bn+relu+conv2+bn+relu fully in LDS -> y2flat
//   gemm(fc): y2flat[3200,3136] @ fc_w^T -> vis[3200,512]
//   25x { q-GEMM(ksplit8) ; flash-attn (single enc pass, online softmax) ;
//         gates ih-GEMM + hh-GEMM (ksplit2 each, partials) ; lstm pointwise ;
//         actor+logits+argmax+embed }
// ---------------------------------------------------------------------------

#define NB   128
#define NT   25
#define NL   512
#define DH   1024
#define DF   512
#define DE   128
#define DIN  1664
#define DCAT 2688
#define NV   512

// d_out offsets (floats): actions[128,25,512], scores[128,25,512,1], h, c
#define ACT_OFF 0
#define SC_OFF  1638400
#define H_OFF   3276800
#define C_OFF   3407872

// workspace offsets (floats); total 15,856,256 floats = 63.4 MB
#define WS_W1T   0u          // [512][256]
#define WS_W2T   131072u     // [256][64]
#define WS_APT   147456u     // [2688][128] (actor_w col-permuted to xcat order)
#define WS_EWT   491520u     // [128][512]
#define WS_BSUM  557056u     // [4096]
#define WS_A1    561152u     // [256]
#define WS_B1    561408u     // [256]
#define WS_A2    561664u     // [64]
#define WS_B2    561728u     // [64]
#define WS_XCAT  561792u     // [128][2688] = [inp(1664) | h(1024)]
#define WS_CBUF  905856u     // [128][1024]
#define WS_QPART 1036928u    // [8][128][1024]
#define WS_GPART 2085504u    // [4][128][4096]
#define WS_VIS   4182656u    // [3200][512]
#define WS_Y2F   5821056u    // [3200][3136]

// ---------------------------------------------------------------------------
__global__ __launch_bounds__(256) void k_prep(
    const float* __restrict__ conv1_w, const float* __restrict__ conv1_b,
    const float* __restrict__ bn1_g, const float* __restrict__ bn1_b,
    const float* __restrict__ bn1_m, const float* __restrict__ bn1_v,
    const float* __restrict__ conv2_w, const float* __restrict__ conv2_b,
    const float* __restrict__ bn2_g, const float* __restrict__ bn2_b,
    const float* __restrict__ bn2_m, const float* __restrict__ bn2_v,
    const float* __restrict__ actor_w, const float* __restrict__ emb_w,
    const float* __restrict__ b_ih, const float* __restrict__ b_hh,
    float* __restrict__ ws)
{
  int i = blockIdx.x * 256 + threadIdx.x;
  if (i < 131072) {                      // W1T[c][o] = conv1_w[o][c]
    int c = i >> 8, o = i & 255;
    ws[WS_W1T + i] = conv1_w[o * 512 + c];
    return;
  }
  i -= 131072;
  if (i < 16384) {                       // W2T[c][o] = conv2_w[o][c]
    int c = i >> 6, o = i & 63;
    ws[WS_W2T + i] = conv2_w[o * 256 + c];
    return;
  }
  i -= 16384;
  if (i < 344064) {                      // APT[k][o], cont=[h|inp] -> xcat=[inp|h]
    int k = i >> 7, o = i & 127;
    int src = (k < DIN) ? (DH + k) : (k - DIN);
    ws[WS_APT + i] = actor_w[o * DCAT + src];
    return;
  }
  i -= 344064;
  if (i < 65536) {                       // EWT[j][v] = emb_w[v][j]
    int j = i >> 9, v = i & 511;
    ws[WS_EWT + i] = emb_w[v * 128 + j];
    return;
  }
  i -= 65536;
  if (i < 4096) { ws[WS_BSUM + i] = b_ih[i] + b_hh[i]; return; }
  i -= 4096;
  if (i < 256) {
    float a = bn1_g[i] / sqrtf(bn1_v[i] + 1e-5f);
    ws[WS_A1 + i] = a;
    ws[WS_B1 + i] = a * (conv1_b[i] - bn1_m[i]) + bn1_b[i];
    return;
  }
  i -= 256;
  if (i < 64) {
    float a = bn2_g[i] / sqrtf(bn2_v[i] + 1e-5f);
    ws[WS_A2 + i] = a;
    ws[WS_B2 + i] = a * (conv2_b[i] - bn2_m[i]) + bn2_b[i];
  }
}

// ---------------------------------------------------------------------------
__global__ __launch_bounds__(256) void k_init(
    const float* __restrict__ h0, const float* __restrict__ c0,
    const float* __restrict__ go, float* __restrict__ ws)
{
  int b = blockIdx.x, tid = threadIdx.x;
  if (tid < 128) ws[WS_XCAT + b * DCAT + 1536 + tid] = go[tid];
  for (int d = tid; d < 1024; d += 256) {
    ws[WS_XCAT + b * DCAT + 1664 + d] = h0[b * 1024 + d];
    ws[WS_CBUF + b * 1024 + d] = c0[b * 1024 + d];
  }
}

// ---------------------------------------------------------------------------
// One image per block: conv1(512->256)+bn+relu, conv2(256->64)+bn+relu in LDS.
// LDS: 13312 floats (53 KB) -> 3 blocks/CU. Rows padded to 52 for b128 align.
__global__ __launch_bounds__(256) void k_visconv(
    const float* __restrict__ frames, float* __restrict__ ws)
{
  __shared__ float sm[13312];
  const int bt = blockIdx.x, tid = threadIdx.x;
  const float* img = frames + (size_t)bt * 25088;
  const float* W1T = ws + WS_W1T;
  const float* W2T = ws + WS_W2T;

  float acc[13][4];
  #pragma unroll
  for (int q = 0; q < 13; ++q)
    #pragma unroll
    for (int j = 0; j < 4; ++j) acc[q][j] = 0.f;

  for (int cc = 0; cc < 4; ++cc) {      // 4 chunks of 128 input channels
    for (int i4 = tid; i4 < 1568; i4 += 256) {
      float4 v = *(const float4*)(img + cc * 6272 + i4 * 4);
      int gi = i4 * 4;
      #pragma unroll
      for (int j = 0; j < 4; ++j) {
        int e = gi + j, c = e / 49, hw = e - c * 49;
        sm[c * 52 + hw] = (&v.x)[j];
      }
    }
    __syncthreads();
    const int o = tid;
    for (int c = 0; c < 128; ++c) {
      float w = W1T[(cc * 128 + c) * 256 + o];
      const float* xr = &sm[c * 52];
      #pragma unroll
      for (int q = 0; q < 13; ++q) {
        float4 x = *(const float4*)&xr[q * 4];
        acc[q][0] += w * x.x; acc[q][1] += w * x.y;
        acc[q][2] += w * x.z; acc[q][3] += w * x.w;
      }
    }
    __syncthreads();
  }
  {                                      // y1 = relu(a1*acc+b1) -> sm[o*52+hw]
    const int o = tid;
    float aa = ws[WS_A1 + o], bb = ws[WS_B1 + o];
    #pragma unroll
    for (int q = 0; q < 13; ++q)
      #pragma unroll
      for (int j = 0; j < 4; ++j) {
        int hw = q * 4 + j;
        if (hw < 49) sm[o * 52 + hw] = fmaxf(aa * acc[q][j] + bb, 0.f);
      }
  }
  __syncthreads();
  // conv2: o2 = lane (0..63), each wave owns hw-quads {g, g+4, g+8, g+12}
  const int o2 = tid & 63, gq = tid >> 6;
  float acc2[4][4];
  #pragma unroll
  for (int qi = 0; qi < 4; ++qi)
    #pragma unroll
    for (int j = 0; j < 4; ++j) acc2[qi][j] = 0.f;
  for (int c = 0; c < 256; ++c) {
    float w = W2T[c * 64 + o2];
    const float* xr = &sm[c * 52];
    #pragma unroll
    for (int qi = 0; qi < 4; ++qi) {
      int q = gq + qi * 4;
      if (q < 13) {
        float4 x = *(const float4*)&xr[q * 4];
        acc2[qi][0] += w * x.x; acc2[qi][1] += w * x.y;
        acc2[qi][2] += w * x.z; acc2[qi][3] += w * x.w;
      }
    }
  }
  float aa = ws[WS_A2 + o2], bb = ws[WS_B2 + o2];
  float* y2f = ws + WS_Y2F + (size_t)bt * 3136;
  #pragma unroll
  for (int qi = 0; qi < 4; ++qi) {
    int q = gq + qi * 4;
    if (q < 13) {
      #pragma unroll
      for (int j = 0; j < 4; ++j) {
        int hw = q * 4 + j;
        if (hw < 49) y2f[o2 * 49 + hw] = fmaxf(aa * acc2[qi][j] + bb, 0.f);
      }
    }
  }
}

// ---------------------------------------------------------------------------
// Generic fp32 GEMM: C[m,n] (+=slice z) = A[m,:] . B[n,:]  (A:[M,K] lda,
// B:[N,K] ldb row-major). 64x64 block tile, 4x4 thread tile, BK=32,
// optional K-split via blockIdx.z (writes partials at z*strideCz).
__global__ __launch_bounds__(256) void k_gemm(
    const float* __restrict__ A, int lda,
    const float* __restrict__ B, int ldb,
    float* __restrict__ C, int ldc,
    int Kz, const float* __restrict__ bias, long strideCz)
{
  __shared__ float As[32 * 68];
  __shared__ float Bs[32 * 68];
  const int tid = threadIdx.x;
  const int bm = blockIdx.x, bn = blockIdx.y, bz = blockIdx.z;
  const int tm = tid >> 4, tn = tid & 15;
  float acc[4][4];
  #pragma unroll
  for (int i = 0; i < 4; ++i)
    #pragma unroll
    for (int j = 0; j < 4; ++j) acc[i][j] = 0.f;

  const int kbase0 = bz * Kz;
  for (int kk = 0; kk < Kz; kk += 32) {
    const int kb = kbase0 + kk;
    #pragma unroll
    for (int i = 0; i < 8; ++i) {
      const int idx = tid + i * 256;       // 2048 = 64 rows x 32 k
      const int mm = idx >> 5, k = idx & 31;
      As[k * 68 + mm] = A[(size_t)(bm * 64 + mm) * lda + kb + k];
      Bs[k * 68 + mm] = B[(size_t)(bn * 64 + mm) * ldb + kb + k];
    }
    __syncthreads();
    #pragma unroll
    for (int k = 0; k < 32; ++k) {
      const float4 a4 = *(const float4*)&As[k * 68 + tm * 4];
      const float4 b4 = *(const float4*)&Bs[k * 68 + tn * 4];
      acc[0][0] += a4.x*b4.x; acc[0][1] += a4.x*b4.y; acc[0][2] += a4.x*b4.z; acc[0][3] += a4.x*b4.w;
      acc[1][0] += a4.y*b4.x; acc[1][1] += a4.y*b4.y; acc[1][2] += a4.y*b4.z; acc[1][3] += a4.y*b4.w;
      acc[2][0] += a4.z*b4.x; acc[2][1] += a4.z*b4.y; acc[2][2] += a4.z*b4.z; acc[2][3] += a4.z*b4.w;
      acc[3][0] += a4.w*b4.x; acc[3][1] += a4.w*b4.y; acc[3][2] += a4.w*b4.z; acc[3][3] += a4.w*b4.w;
    }
    __syncthreads();
  }
  float* Cz = C + (size_t)bz * strideCz;
  #pragma unroll
  for (int i = 0; i < 4; ++i) {
    const int row = bm * 64 + tm * 4 + i;
    const int col0 = bn * 64 + tn * 4;
    float4 v;
    v.x = acc[i][0]; v.y = acc[i][1]; v.z = acc[i][2]; v.w = acc[i][3];
    if (bias) {
      v.x += bias[col0]; v.y += bias[col0 + 1];
      v.z += bias[col0 + 2]; v.w += bias[col0 + 3];
    }
    *(float4*)&Cz[(size_t)row * ldc + col0] = v;
  }
}

// ---------------------------------------------------------------------------
// Flash-style attention, one block per batch element, 512 threads = 8 waves.
// Single pass over enc: raw scores + online-softmax weighted sum.
// Epilogue writes scores to d_out, weighted + vis_t into xcat.
__global__ __launch_bounds__(512) void k_attn(
    const float* __restrict__ enc, const float* __restrict__ hfc_b,
    float* __restrict__ ws, float* __restrict__ out, int t)
{
  __shared__ float q_lds[1024];
  __shared__ float raw_lds[512];
  __shared__ float accw[8][1024];
  __shared__ float m_lds[8];
  __shared__ float z_lds[8];
  const int b = blockIdx.x, tid = threadIdx.x;
  const float* qpart = ws + WS_QPART;
  for (int d = tid; d < 1024; d += 512) {
    float s = hfc_b[d];
    #pragma unroll
    for (int sp = 0; sp < 8; ++sp) s += qpart[sp * 131072 + b * 1024 + d];
    q_lds[d] = s;
  }
  __syncthreads();
  const int lane = tid & 63, wv = tid >> 6;
  const float4 q0 = *(const float4*)&q_lds[lane * 4];
  const float4 q1 = *(const float4*)&q_lds[lane * 4 + 256];
  const float4 q2 = *(const float4*)&q_lds[lane * 4 + 512];
  const float4 q3 = *(const float4*)&q_lds[lane * 4 + 768];
  const float* row = enc + (size_t)b * (NL * DH) + lane * 4;
  float m = -INFINITY, z = 0.f;
  float4 ac0 = {0,0,0,0}, ac1 = {0,0,0,0}, ac2 = {0,0,0,0}, ac3 = {0,0,0,0};
  float4 e0 = *(const float4*)&row[wv * 1024];
  float4 e1 = *(const float4*)&row[wv * 1024 + 256];
  float4 e2 = *(const float4*)&row[wv * 1024 + 512];
  float4 e3 = *(const float4*)&row[wv * 1024 + 768];
  for (int r = 0; r < 64; ++r) {
    const int l = wv + (r << 3);
    const float4 c0_ = e0, c1_ = e1, c2_ = e2, c3_ = e3;
    if (r < 63) {
      const int ln = (l + 8) * 1024;
      e0 = *(const float4*)&row[ln];
      e1 = *(const float4*)&row[ln + 256];
      e2 = *(const float4*)&row[ln + 512];
      e3 = *(const float4*)&row[ln + 768];
    }
    float d = c0_.x*q0.x + c0_.y*q0.y + c0_.z*q0.z + c0_.w*q0.w;
    d += c1_.x*q1.x + c1_.y*q1.y + c1_.z*q1.z + c1_.w*q1.w;
    d += c2_.x*q2.x + c2_.y*q2.y + c2_.z*q2.z + c2_.w*q2.w;
    d += c3_.x*q3.x + c3_.y*q3.y + c3_.z*q3.z + c3_.w*q3.w;
    #pragma unroll
    for (int off = 32; off > 0; off >>= 1) d += __shfl_xor(d, off, 64);
    if (lane == 0) raw_lds[l] = d;
    const float mn = fmaxf(m, d);
    const float sc = expf(m - mn);
    const float p  = expf(d - mn);
    z = z * sc + p;
    ac0.x = ac0.x*sc + p*c0_.x; ac0.y = ac0.y*sc + p*c0_.y; ac0.z = ac0.z*sc + p*c0_.z; ac0.w = ac0.w*sc + p*c0_.w;
    ac1.x = ac1.x*sc + p*c1_.x; ac1.y = ac1.y*sc + p*c1_.y; ac1.z = ac1.z*sc + p*c1_.z; ac1.w = ac1.w*sc + p*c1_.w;
    ac2.x = ac2.x*sc + p*c2_.x; ac2.y = ac2.y*sc + p*c2_.y; ac2.z = ac2.z*sc + p*c2_.z; ac2.w = ac2.w*sc + p*c2_.w;
    ac3.x = ac3.x*sc + p*c3_.x; ac3.y = ac3.y*sc + p*c3_.y; ac3.z = ac3.z*sc + p*c3_.z; ac3.w = ac3.w*sc + p*c3_.w;
    m = mn;
  }
  *(float4*)&accw[wv][lane * 4      ] = ac0;
  *(float4*)&accw[wv][lane * 4 + 256] = ac1;
  *(float4*)&accw[wv][lane * 4 + 512] = ac2;
  *(float4*)&accw[wv][lane * 4 + 768] = ac3;
  if (lane == 0) { m_lds[wv] = m; z_lds[wv] = z; }
  __syncthreads();
  float M = m_lds[0];
  #pragma unroll
  for (int s = 1; s < 8; ++s) M = fmaxf(M, m_lds[s]);
  float Z = 0.f;
  #pragma unroll
  for (int s = 0; s < 8; ++s) Z += expf(m_lds[s] - M) * z_lds[s];
  const float inv = 1.f / Z;
  for (int d = tid; d < 1024; d += 512) {
    float wsum = 0.f;
    #pragma unroll
    for (int s = 0; s < 8; ++s) wsum += expf(m_lds[s] - M) * accw[s][d];
    ws[WS_XCAT + b * DCAT + 512 + d] = wsum * inv;
  }
  out[SC_OFF + ((size_t)b * NT + t) * NL + tid] = expf(raw_lds[tid] - M) * inv;
  ws[WS_XCAT + b * DCAT + tid] = ws[WS_VIS + ((size_t)b * NT + t) * DF + tid];
}

// ---------------------------------------------------------------------------
__global__ __launch_bounds__(256) void k_lstm(
    float* __restrict__ ws, float* __restrict__ out, int last)
{
  const int id = blockIdx.x * 256 + threadIdx.x;  // [0, 131072)
  const int b = id >> 10, j = id & 1023;
  const float* gpart = ws + WS_GPART;
  const float* bsum = ws + WS_BSUM;
  float g[4];
  #pragma unroll
  for (int gi = 0; gi < 4; ++gi) {
    const int x = gi * 1024 + j;
    float s = bsum[x];
    #pragma unroll
    for (int sp = 0; sp < 4; ++sp) s += gpart[(size_t)sp * 524288 + b * 4096 + x];
    g[gi] = s;
  }
  const float ii = 1.f / (1.f + expf(-g[0]));
  const float ff = 1.f / (1.f + expf(-g[1]));
  const float gg = tanhf(g[2]);
  const float oo = 1.f / (1.f + expf(-g[3]));
  const float c = ff * ws[WS_CBUF + id] + ii * gg;
  const float h = oo * tanhf(c);
  ws[WS_CBUF + id] = c;
  ws[WS_XCAT + b * DCAT + 1664 + j] = h;
  if (last) { out[H_OFF + id] = h; out[C_OFF + id] = c; }
}

// ---------------------------------------------------------------------------
// actor: action_emb = [inp|h].actor_wP + b; logits = action_emb.emb_w^T;
// write logits, argmax (first-max tie rule), feed e_t back into xcat.
__global__ __launch_bounds__(256) void k_actor(
    const float* __restrict__ emb_w, const float* __restrict__ actor_b,
    float* __restrict__ ws, float* __restrict__ out, int t)
{
  __shared__ float xl[DCAT];
  __shared__ float ph[256];
  __shared__ float ae[128];
  __shared__ float bv[256];
  __shared__ int   bi[256];
  const int b = blockIdx.x, tid = threadIdx.x;
  float* xcat = ws + WS_XCAT + (size_t)b * DCAT;
  for (int i = tid; i < DCAT / 4; i += 256)
    ((float4*)xl)[i] = ((const float4*)xcat)[i];
  __syncthreads();
  {
    const int o = tid & 127;
    const int k0 = (tid >> 7) * 1344;
    const float* APT = ws + WS_APT;
    float s = 0.f;
    #pragma unroll 8
    for (int k = k0; k < k0 + 1344; ++k) s += xl[k] * APT[k * 128 + o];
    ph[tid] = s;
  }
  __syncthreads();
  if (tid < 128) ae[tid] = ph[tid] + ph[tid + 128] + actor_b[tid];
  __syncthreads();
  const float* EWT = ws + WS_EWT;
  float best = -INFINITY; int besti = 0;
  for (int v = tid; v < NV; v += 256) {
    float s = 0.f;
    #pragma unroll 8
    for (int j = 0; j < 128; ++j) s += ae[j] * EWT[j * 512 + v];
    out[ACT_OFF + ((size_t)b * NT + t) * NV + v] = s;
    if (s > best) { best = s; besti = v; }
  }
  bv[tid] = best; bi[tid] = besti;
  __syncthreads();
  for (int s2 = 128; s2 > 0; s2 >>= 1) {
    if (tid < s2) {
      float ov = bv[tid + s2]; int oi = bi[tid + s2];
      if (ov > bv[tid] || (ov == bv[tid] && oi < bi[tid])) { bv[tid] = ov; bi[tid] = oi; }
    }
    __syncthreads();
  }
  const int am = bi[0];
  if (tid < 128) xcat[1536 + tid] = emb_w[am * 128 + tid];
}

// ---------------------------------------------------------------------------
extern "C" void kernel_launch(void* const* d_in, const int* in_sizes, int n_in,
                              void* d_out, int out_size, void* d_ws, size_t ws_size,
                              hipStream_t stream)
{
  const float* enc     = (const float*)d_in[0];
  const float* frames  = (const float*)d_in[1];
  const float* h0      = (const float*)d_in[2];
  const float* c0      = (const float*)d_in[3];
  // d_in[4] = max_decode (25, == T) — loop count fixed at compile time
  const float* emb_w   = (const float*)d_in[5];
  const float* go      = (const float*)d_in[6];
  const float* conv1_w = (const float*)d_in[7];
  const float* conv1_b = (const float*)d_in[8];
  const float* bn1_g   = (const float*)d_in[9];
  const float* bn1_b   = (const float*)d_in[10];
  const float* bn1_m   = (const float*)d_in[11];
  const float* bn1_v   = (const float*)d_in[12];
  const float* conv2_w = (const float*)d_in[13];
  const float* conv2_b = (const float*)d_in[14];
  const float* bn2_g   = (const float*)d_in[15];
  const float* bn2_b   = (const float*)d_in[16];
  const float* bn2_m   = (const float*)d_in[17];
  const float* bn2_v   = (const float*)d_in[18];
  const float* fc_w    = (const float*)d_in[19];
  const float* fc_b    = (const float*)d_in[20];
  const float* hfc_w   = (const float*)d_in[21];
  const float* hfc_b   = (const float*)d_in[22];
  const float* w_ih    = (const float*)d_in[23];
  const float* w_hh    = (const float*)d_in[25];
  const float* actor_b = (const float*)d_in[28];
  float* out = (float*)d_out;
  float* ws  = (float*)d_ws;
  const float* b_ih = (const float*)d_in[24];
  const float* b_hh = (const float*)d_in[26];
  const float* actor_w = (const float*)d_in[27];

  k_prep<<<2194, 256, 0, stream>>>(conv1_w, conv1_b, bn1_g, bn1_b, bn1_m, bn1_v,
      conv2_w, conv2_b, bn2_g, bn2_b, bn2_m, bn2_v, actor_w, emb_w, b_ih, b_hh, ws);
  k_init<<<128, 256, 0, stream>>>(h0, c0, go, ws);
  k_visconv<<<3200, 256, 0, stream>>>(frames, ws);
  // fc: vis[3200,512] = y2f[3200,3136] @ fc_w^T + fc_b
  k_gemm<<<dim3(50, 8, 1), 256, 0, stream>>>(ws + WS_Y2F, 3136, fc_w, 3136,
      ws + WS_VIS, 512, 3136, fc_b, 0);

  for (int t = 0; t < NT; ++t) {
    // q partials: h @ hfc_w^T  (K=1024 split 8)
    k_gemm<<<dim3(2, 16, 8), 256, 0, stream>>>(ws + WS_XCAT + 1664, DCAT,
        hfc_w, 1024, ws + WS_QPART, 1024, 128, nullptr, 131072);
    k_attn<<<128, 512, 0, stream>>>(enc, hfc_b, ws, out, t);
    // gates partials: inp @ w_ih^T (K=1664 split 2) ; h @ w_hh^T (K=1024 split 2)
    k_gemm<<<dim3(2, 64, 2), 256, 0, stream>>>(ws + WS_XCAT, DCAT,
        w_ih, 1664, ws + WS_GPART, 4096, 832, nullptr, 524288);
    k_gemm<<<dim3(2, 64, 2), 256, 0, stream>>>(ws + WS_XCAT + 1664, DCAT,
        w_hh, 1024, ws + WS_GPART + 2 * 524288, 4096, 512, nullptr, 524288);
    k_lstm<<<512, 256, 0, stream>>>(ws, out, t == NT - 1 ? 1 : 0);
    k_actor<<<128, 256, 0, stream>>>(emb_w, actor_b, ws, out, t);
  }
}